// Round 9
// baseline (296.682 us; speedup 1.0000x reference)
//
#include <hip/hip_runtime.h>

#define B_DIM   2048
#define IN_DIM  4096
#define OUT_DIM 4096
#define FAN     64

// R13b: single FUSED kernel (no pack, no reorder, no workspace). Resubmit of
// R13 after infra failure ("container failed twice" = acquire-side; kernel
// re-audited: LDS/global bounds exact, swizzle bijective, uniform barriers).
//  R12 lessons: (a) random-b128 gather cost (~29.5 cyc/op) is address-
//  divergence, not bank imbalance (balancing cut conflicts 22%, time 2%);
//  per-op cost by width: b32 11.6 / b64 ~16 / b128 29.5 at 64 distinct addrs
//  -> fewest DISTINCT addresses at moderate width wins. (b) helper kernels
//  cost more e2e than they save in-kernel. (c) e2e - condensed ~= 80 us =
//  pack kernel + launches + ws round-trip -> fuse everything.
//  Design:
//   - 512 thr, launch_bounds(512,1) (2nd arg = min WG/CU; cap 256 VGPR).
//     Grid (16,16) = 256 blocks = 1/CU. Block: 128 rows x 256 outputs.
//   - In-kernel staging: fp32 rows -> regs (16x dwordx4, coalesced) ->
//     bf16-rne -> ds_write_b128 into a 2 x 64 KB double buffer. Blocks
//     sharing a row-chunk share blockIdx.x%8 -> same XCD -> the 16x fp32
//     re-read stays in that XCD's 4 MB L2.
//   - Cell = 16 B = 8 rows of one column at swizzled byte addr
//     phi(c) = (c>>5)<<9 | (c&3)<<7 | ((c>>2)&7)<<4 (bijective / 64 KB);
//     write side phi(k*2048+tid*4+i) = k*32768 | (tid>>3)<<9 | i<<7 |
//     (tid&7)<<4 -> reg-staged writes bank-equivalent to contiguous; gather
//     uses phi(idx) precomputed into addrs[] (zero per-op cost).
//   - CONVERGENT-PAIR gather: lanes (2k,2k+1) serve ONE output o; even lane
//     reads cell bytes [0,8) = rows 0-3, odd [8,16) = rows 4-7 (ds_read_b64:
//     32 distinct addrs/wave-op, pair-contiguous). 8192 ops/CU predicted
//     ~8-10 cyc/op vs R12's 4096 x 29.5.

typedef float v2f __attribute__((ext_vector_type(2)));

__device__ __forceinline__ unsigned bf16_rne(float f) {
    unsigned u = __float_as_uint(f);
    return (u + 0x7fffu + ((u >> 16) & 1u)) >> 16;   // round-to-nearest-even bf16
}

__device__ __forceinline__ float f4e(const float4& v, int i) {
    return reinterpret_cast<const float*>(&v)[i];
}

// ---- stage: load 8 rows x (two 16-B col-chunks) of tile t into st[16] ----
#define LOADT(t)                                                              \
    {                                                                         \
        const float* s0 = input + (size_t)(rowbase + 8 * (t)) * IN_DIM + (tid << 2); \
        _Pragma("unroll")                                                     \
        for (int r = 0; r < 8; ++r) {                                         \
            st[r]     = *reinterpret_cast<const float4*>(s0 + (size_t)r * IN_DIM);        \
            st[8 + r] = *reinterpret_cast<const float4*>(s0 + (size_t)r * IN_DIM + 2048); \
        }                                                                     \
    }

// ---- convert st[] -> bf16 cells, write to buffer BUF with phi swizzle ----
// cell c = k*2048 + tid*4 + i lives at byte
//   k*32768 + (tid>>3)*512 + i*128 + (tid&7)*16   ( == phi(c) )
#define CWRITE(BUF)                                                           \
    {                                                                         \
        _Pragma("unroll")                                                     \
        for (int k = 0; k < 2; ++k) {                                         \
            _Pragma("unroll")                                                 \
            for (int i = 0; i < 4; ++i) {                                     \
                uint4 q;                                                      \
                q.x = bf16_rne(f4e(st[8*k+0], i)) | (bf16_rne(f4e(st[8*k+1], i)) << 16); \
                q.y = bf16_rne(f4e(st[8*k+2], i)) | (bf16_rne(f4e(st[8*k+3], i)) << 16); \
                q.z = bf16_rne(f4e(st[8*k+4], i)) | (bf16_rne(f4e(st[8*k+5], i)) << 16); \
                q.w = bf16_rne(f4e(st[8*k+6], i)) | (bf16_rne(f4e(st[8*k+7], i)) << 16); \
                *reinterpret_cast<uint4*>(ldsw + (BUF) + k * 32768             \
                    + ((tid >> 3) << 9) + (i << 7) + ((tid & 7) << 4)) = q;    \
            }                                                                 \
        }                                                                     \
    }

// ---- convergent-pair gather of tile t from buffer BUF + store 4 rows ----
#define GATHER(BUF, t)                                                        \
    {                                                                         \
        v2f a01 = {0.f, 0.f}, a23 = {0.f, 0.f};                               \
        _Pragma("unroll")                                                     \
        for (int j = 0; j < FAN; ++j) {                                       \
            const uint2 g = *reinterpret_cast<const uint2*>(ldsb + (BUF) + addrs[j]); \
            const v2f w2 = {wv[j], wv[j]};                                    \
            v2f v;                                                            \
            v.x = __uint_as_float(g.x << 16);                                 \
            v.y = __uint_as_float(g.x & 0xffff0000u);                         \
            a01 = __builtin_elementwise_fma(v, w2, a01);                      \
            v.x = __uint_as_float(g.y << 16);                                 \
            v.y = __uint_as_float(g.y & 0xffff0000u);                         \
            a23 = __builtin_elementwise_fma(v, w2, a23);                      \
        }                                                                     \
        float* op = out + (size_t)(rowbase + 8 * (t) + ((tid & 1) << 2)) * OUT_DIM + o; \
        op[0 * OUT_DIM] = a01.x + bv;                                         \
        op[1 * OUT_DIM] = a01.y + bv;                                         \
        op[2 * OUT_DIM] = a23.x + bv;                                         \
        op[3 * OUT_DIM] = a23.y + bv;                                         \
    }

__global__ __launch_bounds__(512, 1) void fused_kernel(
    const float* __restrict__ input,
    const float* __restrict__ weight,
    const float* __restrict__ bias,
    const int*   __restrict__ mask,
    float*       __restrict__ out)
{
    __shared__ __align__(16) uint4 lds[8192];         // 128 KB = 2 x 64 KB buffers

    const int tid     = threadIdx.x;
    const int o       = blockIdx.y * 256 + (tid >> 1);  // lane pair shares output
    const int rowbase = blockIdx.x * 128;               // 128 rows = 16 tiles of 8

    // ---- per-thread: swizzled cell addrs (+ pair-half offset) + weights ----
    unsigned addrs[FAN];
    float    wv[FAN];
    {
        const int4*   mv = reinterpret_cast<const int4*>(mask)     + o * (FAN / 4);
        const float4* wp = reinterpret_cast<const float4*>(weight) + o * (FAN / 4);
        const unsigned hoff = (unsigned)(tid & 1) << 3;   // 0 / 8 B: rows 0-3 vs 4-7
        #pragma unroll
        for (int j = 0; j < FAN / 4; ++j) {
            int4   m4 = mv[j];
            float4 w4 = wp[j];
            int id;
            id = m4.x; addrs[4*j+0] = (((unsigned)id >> 5) << 9) | (((unsigned)id & 3) << 7) | ((((unsigned)id >> 2) & 7) << 4) | hoff;
            id = m4.y; addrs[4*j+1] = (((unsigned)id >> 5) << 9) | (((unsigned)id & 3) << 7) | ((((unsigned)id >> 2) & 7) << 4) | hoff;
            id = m4.z; addrs[4*j+2] = (((unsigned)id >> 5) << 9) | (((unsigned)id & 3) << 7) | ((((unsigned)id >> 2) & 7) << 4) | hoff;
            id = m4.w; addrs[4*j+3] = (((unsigned)id >> 5) << 9) | (((unsigned)id & 3) << 7) | ((((unsigned)id >> 2) & 7) << 4) | hoff;
            wv[4*j+0] = w4.x;
            wv[4*j+1] = w4.y;
            wv[4*j+2] = w4.z;
            wv[4*j+3] = w4.w;
        }
    }
    const float bv = bias[o];

    const char* ldsb = reinterpret_cast<const char*>(lds);
    char*       ldsw = reinterpret_cast<char*>(lds);
    float4 st[16];

    // ---- prologue: stage tile 0 -> buf0 ----
    LOADT(0);
    CWRITE(0);
    __syncthreads();

    for (int hp = 0; hp < 8; ++hp) {
        // stage A: issue loads(2hp+1) early; gather tile 2hp from buf0;
        //          convert+write tile 2hp+1 -> buf1 (free since last barrier)
        LOADT(2 * hp + 1);
        GATHER(0, 2 * hp);
        CWRITE(65536);
        __syncthreads();

        // stage B: loads(2hp+2); gather tile 2hp+1 from buf1; write -> buf0
        if (hp < 7) {
            LOADT(2 * hp + 2);
            GATHER(65536, 2 * hp + 1);
            CWRITE(0);
        } else {
            GATHER(65536, 2 * hp + 1);
        }
        __syncthreads();
    }
}

extern "C" void kernel_launch(void* const* d_in, const int* in_sizes, int n_in,
                              void* d_out, int out_size, void* d_ws, size_t ws_size,
                              hipStream_t stream) {
    const float* input  = (const float*)d_in[0];
    const float* weight = (const float*)d_in[1];
    const float* bias   = (const float*)d_in[2];
    const int*   mask   = (const int*)d_in[3];
    float*       out    = (float*)d_out;
    (void)d_ws; (void)ws_size;

    dim3 grid(16, 16);  // x = row-chunks (XCD-coherent), y = o-chunks
    fused_kernel<<<grid, 512, 0, stream>>>(input, weight, bias, mask, out);
}